// Round 6
// baseline (32.666 us; speedup 1.0000x reference)
//
#include <hip/hip_runtime.h>
#include <math.h>

#define BLOCK  256
#define GRID   1024
#define NCOMP  7

// Per-walker evaluation with HW approx intrinsics.
// Accumulates 7 real moments: a11 += Psi1*H1, a22 += Psi2*H2, a12 += Psi1*H2,
// a21 += Psi2*H1, p11 += Psi1^2, p22 += Psi2^2, p12 += Psi1*Psi2.
__device__ __forceinline__ void walker_accum(
    float x0, float y0, float z0, float x1, float y1, float z1,
    float Z, float zz, float ch, float K1, float K2,
    float& a11, float& a22, float& a12, float& a21,
    float& p11, float& p22, float& p12)
{
    float rr0 = x0*x0 + y0*y0 + z0*z0;
    float rr1 = x1*x1 + y1*y1 + z1*z1;
    float q0  = __builtin_amdgcn_rsqf(rr0);      // 1/r0
    float q1  = __builtin_amdgcn_rsqf(rr1);      // 1/r1
    float r0  = rr0 * q0;
    float r1  = rr1 * q1;

    // h = exp(-0.5 Z r) = 2^(ch * r),  ch = -0.5 Z log2(e)
    float h0 = __builtin_amdgcn_exp2f(ch * r0);
    float h1 = __builtin_amdgcn_exp2f(ch * r1);
    float hh = h0 * h1;

    float Psi1 = K1 * (hh * hh);                          // prod psi100
    float Psi2 = K2 * (2.0f - Z*r0) * (2.0f - Z*r1) * hh; // prod psi200

    float sinv = q0 + q1;

    float dx = x0 - x1, dy = y0 - y1, dz = z0 - z1;
    float dd = dx*dx + dy*dy + dz*dz;
    float V  = -__builtin_amdgcn_rsqf(dd);       // -1/d12  (VB = 1)

    // -0.5*lap1 = Z*sinv - Z^2 ; -0.5*lap2 = Z*sinv - 0.25 Z^2
    float t1 = Z * sinv - zz + V;
    float t2 = Z * sinv - 0.25f * zz + V;
    float H1 = t1 * Psi1;
    float H2 = t2 * Psi2;

    a11 += Psi1 * H1;
    a22 += Psi2 * H2;
    a12 += Psi1 * H2;
    a21 += Psi2 * H1;
    p11 += Psi1 * Psi1;
    p22 += Psi2 * Psi2;
    p12 += Psi1 * Psi2;
}

__global__ __launch_bounds__(BLOCK) void wvfn_onepass(
    const float4* __restrict__ Rs4,   // float4 view of [N,2,3] f32
    const float* __restrict__ a_p,
    const float* __restrict__ c1r_p, const float* __restrict__ c1i_p,
    const float* __restrict__ c2r_p, const float* __restrict__ c2i_p,
    double* __restrict__ partials,    // SoA: [NCOMP][GRID]
    unsigned int* __restrict__ counter,
    float* __restrict__ out, int out_size, int npairs)
{
    const float Z  = 1.0f / a_p[0];
    const float zz = Z * Z;
    const float ch = -0.5f * Z * 1.4426950408889634f;   // -0.5 Z log2(e)
    const float Y00sq = 0.07957747154594767f;           // 1/(4*pi)
    const float Z3 = Z * zz;
    const float K1 = 4.0f * Z3 * Y00sq;                 // (2 Z^1.5 Y00)^2
    const float K2 = 0.125f * Z3 * Y00sq;               // (Z^1.5 Y00 / (2 sqrt 2))^2

    float a11 = 0.f, a22 = 0.f, a12 = 0.f, a21 = 0.f;
    float p11 = 0.f, p22 = 0.f, p12 = 0.f;

    const int tid    = blockIdx.x * BLOCK + threadIdx.x;
    const int stride = GRID * BLOCK;
    for (int j = tid; j < npairs; j += stride) {
        float4 v0 = Rs4[3*j + 0];
        float4 v1 = Rs4[3*j + 1];
        float4 v2 = Rs4[3*j + 2];
        walker_accum(v0.x, v0.y, v0.z, v0.w, v1.x, v1.y,
                     Z, zz, ch, K1, K2, a11, a22, a12, a21, p11, p22, p12);
        walker_accum(v1.z, v1.w, v2.x, v2.y, v2.z, v2.w,
                     Z, zz, ch, K1, K2, a11, a22, a12, a21, p11, p22, p12);
    }

    double s[NCOMP] = { (double)a11, (double)a22, (double)a12, (double)a21,
                        (double)p11, (double)p22, (double)p12 };

    // wave(64) butterfly reduce
    for (int off = 32; off > 0; off >>= 1) {
        #pragma unroll
        for (int c = 0; c < NCOMP; ++c) s[c] += __shfl_down(s[c], off);
    }

    __shared__ double sm[NCOMP][BLOCK / 64];
    __shared__ bool isLast;
    int wid  = threadIdx.x >> 6;
    int lane = threadIdx.x & 63;
    if (lane == 0) {
        #pragma unroll
        for (int c = 0; c < NCOMP; ++c) sm[c][wid] = s[c];
    }
    __syncthreads();
    if (threadIdx.x == 0) {
        // relaxed agent-scope coherent stores (write to coherence point, NO
        // release fence -> no buffer_wbl2 L2 flush, the R4 killer)
        #pragma unroll
        for (int c = 0; c < NCOMP; ++c) {
            double t = 0.0;
            for (int w = 0; w < BLOCK / 64; ++w) t += sm[c][w];
            __hip_atomic_store(&partials[c * GRID + blockIdx.x], t,
                               __ATOMIC_RELAXED, __HIP_MEMORY_SCOPE_AGENT);
        }
        // wait for our stores to be ACKed at the coherence point, then ticket
        asm volatile("s_waitcnt vmcnt(0)" ::: "memory");
        unsigned int prev = __hip_atomic_fetch_add(
            counter, 1u, __ATOMIC_RELAXED, __HIP_MEMORY_SCOPE_AGENT);
        isLast = (prev == (unsigned int)(GRID - 1));
    }
    __syncthreads();

    if (!isLast) return;

    // last block: reduce all partials (coherent relaxed loads), finish, write
    double u[NCOMP];
    #pragma unroll
    for (int c = 0; c < NCOMP; ++c) u[c] = 0.0;
    for (int b = threadIdx.x; b < GRID; b += BLOCK) {
        #pragma unroll
        for (int c = 0; c < NCOMP; ++c)
            u[c] += __hip_atomic_load(&partials[c * GRID + b],
                                      __ATOMIC_RELAXED, __HIP_MEMORY_SCOPE_AGENT);
    }
    for (int off = 32; off > 0; off >>= 1) {
        #pragma unroll
        for (int c = 0; c < NCOMP; ++c) u[c] += __shfl_down(u[c], off);
    }
    if (lane == 0) {
        #pragma unroll
        for (int c = 0; c < NCOMP; ++c) sm[c][wid] = u[c];
    }
    __syncthreads();
    if (threadIdx.x == 0) {
        double A11 = 0, A22 = 0, A12 = 0, A21 = 0, P11 = 0, P22 = 0, P12 = 0;
        for (int w = 0; w < BLOCK / 64; ++w) {
            A11 += sm[0][w]; A22 += sm[1][w]; A12 += sm[2][w]; A21 += sm[3][w];
            P11 += sm[4][w]; P22 += sm[5][w]; P12 += sm[6][w];
        }
        // psistar*H_psi = |c1|^2 A11 + |c2|^2 A22 + conj(c1)c2 A12 + c1 conj(c2) A21
        // psistar*psi   = |c1|^2 P11 + |c2|^2 P22 + 2 Re(conj(c1)c2) P12   (real)
        double c1r = (double)c1r_p[0], c1i = (double)c1i_p[0];
        double c2r = (double)c2r_p[0], c2i = (double)c2i_p[0];
        double m1 = c1r*c1r + c1i*c1i;          // |c1|^2
        double m2 = c2r*c2r + c2i*c2i;          // |c2|^2
        double uu = c1r*c2r + c1i*c2i;          // Re(conj(c1) c2)
        double vv = c1r*c2i - c1i*c2r;          // Im(conj(c1) c2)

        double Hre = m1*A11 + m2*A22 + uu*(A12 + A21);
        double Him = vv*(A12 - A21);
        double Den = m1*P11 + m2*P22 + 2.0*uu*P12;

        out[0] = (float)(Hre / Den);
        if (out_size > 1) out[1] = (float)(Him / Den);
    }
}

extern "C" void kernel_launch(void* const* d_in, const int* in_sizes, int n_in,
                              void* d_out, int out_size, void* d_ws, size_t ws_size,
                              hipStream_t stream) {
    const float4* Rs4 = (const float4*)d_in[0];
    const float* a_p  = (const float*)d_in[1];
    const float* c1r  = (const float*)d_in[2];
    const float* c1i  = (const float*)d_in[3];
    const float* c2r  = (const float*)d_in[4];
    const float* c2i  = (const float*)d_in[5];

    int N      = in_sizes[0] / 6;   // [N,2,3] f32 -> N walkers
    int npairs = N / 2;

    // d_ws layout: [counter (16B-aligned pad)] [NCOMP*GRID doubles]
    unsigned int* counter  = (unsigned int*)d_ws;
    double*       partials = (double*)((char*)d_ws + 16);

    // reset ticket each call (graph-legal, ~zero work; partials need no init:
    // every slot is overwritten before the ticket permits any read)
    hipMemsetAsync(counter, 0, sizeof(unsigned int), stream);

    wvfn_onepass<<<GRID, BLOCK, 0, stream>>>(Rs4, a_p, c1r, c1i, c2r, c2i,
                                             partials, counter,
                                             (float*)d_out, out_size, npairs);
}

// Round 7
// 21.387 us; speedup vs baseline: 1.5274x; 1.5274x over previous
//
#include <hip/hip_runtime.h>
#include <math.h>

#define BLOCK  256
#define GRID   2048
#define NCOMP  7

// Per-walker evaluation with HW approx intrinsics.
// Accumulates 7 real moments: a11 += Psi1*H1, a22 += Psi2*H2, a12 += Psi1*H2,
// a21 += Psi2*H1, p11 += Psi1^2, p22 += Psi2^2, p12 += Psi1*Psi2.
__device__ __forceinline__ void walker_accum(
    float x0, float y0, float z0, float x1, float y1, float z1,
    float Z, float zz, float ch, float K1, float K2,
    float& a11, float& a22, float& a12, float& a21,
    float& p11, float& p22, float& p12)
{
    float rr0 = x0*x0 + y0*y0 + z0*z0;
    float rr1 = x1*x1 + y1*y1 + z1*z1;
    float q0  = __builtin_amdgcn_rsqf(rr0);      // 1/r0
    float q1  = __builtin_amdgcn_rsqf(rr1);      // 1/r1
    float r0  = rr0 * q0;
    float r1  = rr1 * q1;

    // h = exp(-0.5 Z r) = 2^(ch * r),  ch = -0.5 Z log2(e)
    float h0 = __builtin_amdgcn_exp2f(ch * r0);
    float h1 = __builtin_amdgcn_exp2f(ch * r1);
    float hh = h0 * h1;

    float Psi1 = K1 * (hh * hh);                          // prod psi100
    float Psi2 = K2 * (2.0f - Z*r0) * (2.0f - Z*r1) * hh; // prod psi200

    float sinv = q0 + q1;

    float dx = x0 - x1, dy = y0 - y1, dz = z0 - z1;
    float dd = dx*dx + dy*dy + dz*dz;
    float V  = -__builtin_amdgcn_rsqf(dd);       // -1/d12  (VB = 1)

    // -0.5*lap1 = Z*sinv - Z^2 ; -0.5*lap2 = Z*sinv - 0.25 Z^2
    float t1 = Z * sinv - zz + V;
    float t2 = Z * sinv - 0.25f * zz + V;
    float H1 = t1 * Psi1;
    float H2 = t2 * Psi2;

    a11 += Psi1 * H1;
    a22 += Psi2 * H2;
    a12 += Psi1 * H2;
    a21 += Psi2 * H1;
    p11 += Psi1 * Psi1;
    p22 += Psi2 * Psi2;
    p12 += Psi1 * Psi2;
}

__global__ __launch_bounds__(BLOCK) void wvfn_partial(
    const float4* __restrict__ Rs4,   // float4 view of [N,2,3] f32
    const float* __restrict__ a_p,
    float* __restrict__ partials,     // SoA: [NCOMP][GRID] f32
    int npairs)
{
    const float Z  = 1.0f / a_p[0];
    const float zz = Z * Z;
    const float ch = -0.5f * Z * 1.4426950408889634f;   // -0.5 Z log2(e)
    const float Y00sq = 0.07957747154594767f;           // 1/(4*pi)
    const float Z3 = Z * zz;
    const float K1 = 4.0f * Z3 * Y00sq;                 // (2 Z^1.5 Y00)^2
    const float K2 = 0.125f * Z3 * Y00sq;               // (Z^1.5 Y00 / (2 sqrt 2))^2

    float a11 = 0.f, a22 = 0.f, a12 = 0.f, a21 = 0.f;
    float p11 = 0.f, p22 = 0.f, p12 = 0.f;

    const int tid    = blockIdx.x * BLOCK + threadIdx.x;
    const int stride = GRID * BLOCK;

    // 2x unrolled grid-stride: all 6 float4 loads issued before compute.
    // At GRID*BLOCK = 524288 and npairs = 1M, this body covers everything.
    int j = tid;
    for (; j + stride < npairs; j += 2 * stride) {
        int j2 = j + stride;
        float4 v0 = Rs4[3*j  + 0];
        float4 v1 = Rs4[3*j  + 1];
        float4 v2 = Rs4[3*j  + 2];
        float4 w0 = Rs4[3*j2 + 0];
        float4 w1 = Rs4[3*j2 + 1];
        float4 w2 = Rs4[3*j2 + 2];
        walker_accum(v0.x, v0.y, v0.z, v0.w, v1.x, v1.y,
                     Z, zz, ch, K1, K2, a11, a22, a12, a21, p11, p22, p12);
        walker_accum(v1.z, v1.w, v2.x, v2.y, v2.z, v2.w,
                     Z, zz, ch, K1, K2, a11, a22, a12, a21, p11, p22, p12);
        walker_accum(w0.x, w0.y, w0.z, w0.w, w1.x, w1.y,
                     Z, zz, ch, K1, K2, a11, a22, a12, a21, p11, p22, p12);
        walker_accum(w1.z, w1.w, w2.x, w2.y, w2.z, w2.w,
                     Z, zz, ch, K1, K2, a11, a22, a12, a21, p11, p22, p12);
    }
    if (j < npairs) {
        float4 v0 = Rs4[3*j + 0];
        float4 v1 = Rs4[3*j + 1];
        float4 v2 = Rs4[3*j + 2];
        walker_accum(v0.x, v0.y, v0.z, v0.w, v1.x, v1.y,
                     Z, zz, ch, K1, K2, a11, a22, a12, a21, p11, p22, p12);
        walker_accum(v1.z, v1.w, v2.x, v2.y, v2.z, v2.w,
                     Z, zz, ch, K1, K2, a11, a22, a12, a21, p11, p22, p12);
    }

    float s[NCOMP] = { a11, a22, a12, a21, p11, p22, p12 };

    // wave(64) butterfly reduce (f32)
    for (int off = 32; off > 0; off >>= 1) {
        #pragma unroll
        for (int c = 0; c < NCOMP; ++c) s[c] += __shfl_down(s[c], off);
    }

    __shared__ float sm[NCOMP][BLOCK / 64];
    int wid  = threadIdx.x >> 6;
    int lane = threadIdx.x & 63;
    if (lane == 0) {
        #pragma unroll
        for (int c = 0; c < NCOMP; ++c) sm[c][wid] = s[c];
    }
    __syncthreads();
    if (threadIdx.x == 0) {
        #pragma unroll
        for (int c = 0; c < NCOMP; ++c) {
            float t = 0.0f;
            for (int w = 0; w < BLOCK / 64; ++w) t += sm[c][w];
            partials[c * GRID + blockIdx.x] = t;
        }
    }
}

__global__ __launch_bounds__(BLOCK) void wvfn_finish(
    const float4* __restrict__ partials4,  // [NCOMP*GRID/4] float4 view
    const float* __restrict__ c1r_p, const float* __restrict__ c1i_p,
    const float* __restrict__ c2r_p, const float* __restrict__ c2i_p,
    float* __restrict__ out, int out_size)
{
    const int ROWV = GRID / 4;             // float4 per component row
    double u[NCOMP];
    #pragma unroll
    for (int c = 0; c < NCOMP; ++c) u[c] = 0.0;

    for (int i = threadIdx.x; i < NCOMP * ROWV; i += BLOCK) {
        int c = i / ROWV;                  // component of this float4
        float4 v = partials4[i];
        u[c] += (double)((v.x + v.y) + (v.z + v.w));
    }
    for (int off = 32; off > 0; off >>= 1) {
        #pragma unroll
        for (int c = 0; c < NCOMP; ++c) u[c] += __shfl_down(u[c], off);
    }
    __shared__ double sm[NCOMP][BLOCK / 64];
    int wid  = threadIdx.x >> 6;
    int lane = threadIdx.x & 63;
    if (lane == 0) {
        #pragma unroll
        for (int c = 0; c < NCOMP; ++c) sm[c][wid] = u[c];
    }
    __syncthreads();
    if (threadIdx.x == 0) {
        double A11 = 0, A22 = 0, A12 = 0, A21 = 0, P11 = 0, P22 = 0, P12 = 0;
        for (int w = 0; w < BLOCK / 64; ++w) {
            A11 += sm[0][w]; A22 += sm[1][w]; A12 += sm[2][w]; A21 += sm[3][w];
            P11 += sm[4][w]; P22 += sm[5][w]; P12 += sm[6][w];
        }
        // psistar*H_psi = |c1|^2 A11 + |c2|^2 A22 + conj(c1)c2 A12 + c1 conj(c2) A21
        // psistar*psi   = |c1|^2 P11 + |c2|^2 P22 + 2 Re(conj(c1)c2) P12   (real)
        double c1r = (double)c1r_p[0], c1i = (double)c1i_p[0];
        double c2r = (double)c2r_p[0], c2i = (double)c2i_p[0];
        double m1 = c1r*c1r + c1i*c1i;          // |c1|^2
        double m2 = c2r*c2r + c2i*c2i;          // |c2|^2
        double uu = c1r*c2r + c1i*c2i;          // Re(conj(c1) c2)
        double vv = c1r*c2i - c1i*c2r;          // Im(conj(c1) c2)

        double Hre = m1*A11 + m2*A22 + uu*(A12 + A21);
        double Him = vv*(A12 - A21);
        double Den = m1*P11 + m2*P22 + 2.0*uu*P12;

        out[0] = (float)(Hre / Den);
        if (out_size > 1) out[1] = (float)(Him / Den);
    }
}

extern "C" void kernel_launch(void* const* d_in, const int* in_sizes, int n_in,
                              void* d_out, int out_size, void* d_ws, size_t ws_size,
                              hipStream_t stream) {
    const float4* Rs4 = (const float4*)d_in[0];
    const float* a_p  = (const float*)d_in[1];
    const float* c1r  = (const float*)d_in[2];
    const float* c1i  = (const float*)d_in[3];
    const float* c2r  = (const float*)d_in[4];
    const float* c2i  = (const float*)d_in[5];

    int N      = in_sizes[0] / 6;   // [N,2,3] f32 -> N walkers
    int npairs = N / 2;

    float* partials = (float*)d_ws;   // NCOMP*GRID f32 = 56 KB

    wvfn_partial<<<GRID, BLOCK, 0, stream>>>(Rs4, a_p, partials, npairs);
    wvfn_finish<<<1, BLOCK, 0, stream>>>((const float4*)partials,
                                         c1r, c1i, c2r, c2i,
                                         (float*)d_out, out_size);
}